// Round 13
// baseline (114.104 us; speedup 1.0000x reference)
//
#include <hip/hip_runtime.h>

namespace {
constexpr float kLrelu = 0.2f;
constexpr float kEps   = 1e-5f;
}

typedef short bf16x8 __attribute__((ext_vector_type(8)));
typedef float f32x4  __attribute__((ext_vector_type(4)));

// LDS-only barrier: waits local ops, does NOT drain vmcnt -> global prefetch
// loads stay in flight across the barrier.
#define LDS_BARRIER() asm volatile("s_waitcnt lgkmcnt(0)\n\ts_barrier" ::: "memory")

// round-to-nearest-even f32 -> bf16 (inputs are finite)
static __device__ __forceinline__ unsigned f2bf(float x) {
  unsigned u = __float_as_uint(x);
  return (u + 0x7FFFu + ((u >> 16) & 1u)) >> 16;
}
static __device__ __forceinline__ unsigned packbf(float a, float b) {
  return f2bf(a) | (f2bf(b) << 16);
}

// Fully fused grouped conv (bf16 MFMA) + block-local BN + LeakyReLU + fold
// store. Block = (g, zt): 64 z x ALL 512 m. 256 blocks x 512 threads (8 waves,
// wave tile 64z x 64m). DIRECT im2col staging: each staging thread holds one
// full patch row (8 floats) in registers and writes its tap-packs straight
// into Bs in fragment layout -- no raw buffer, no LDS gather round trip.
// Row py serves (oy,ky) pairs with 2oy-1+ky=py; py=0/7 also write the
// zero slices (0,0)/(3,3) (iy=-1 / iy=8). Bs/As layout, frag reads, MFMA,
// BN, store identical to the verified R12 kernel.
__global__ __launch_bounds__(512, 2) void conv_bn_fused(
    const float* __restrict__ input,   // [32,128,64,64]
    const float* __restrict__ weight,  // [16384, 2048]  (k = nc*16 + ky*4 + kx)
    float* __restrict__ out,           // [32,256,32,32] FINAL (post BN+LReLU)
    const float* __restrict__ gamma,
    const float* __restrict__ beta)
{
  // GEMM tiles, row = 64B (32 bf16), 16B-granule XOR swizzle (gk ^ ((row>>1)&3))
  __shared__ __align__(16) char Bs[512 * 64];     // 32 KB
  __shared__ __align__(16) char As[64 * 64];      // 4 KB

  const int bid  = blockIdx.x;
  const int orig = (bid & 7) * 32 + (bid >> 3);   // XCD-chunked (256 % 8 == 0)
  const int g    = orig >> 2;                     // group 0..63
  const int zt   = orig & 3;                      // z tile 0..3
  const int hp = g >> 3, wp = g & 7;
  const int z0 = zt * 64;

  const int tid  = threadIdx.x;
  const int lane = tid & 63;
  const int w    = tid >> 6;                      // wave 0..7, m-range = w*64
  const int llo  = lane & 15, lhi = lane >> 4;

  // -------- staging: thread -> (patch pl, row py); holds the full 8-float row
  const int pl_s  = tid >> 3;                     // 0..63
  const int py_s  = tid & 7;                      // 0..7
  const int bl_s  = pl_s >> 1;                    // b local 0..31
  const int ncs_s = pl_s & 1;
  const float* const gsrc = input
      + ((size_t)bl_s * 128 + ncs_s) * 4096
      + (hp * 8 + py_s) * 64 + wp * 8;            // + ck*8192 per chunk

  // pair enumeration for this row
  const int oy1 = (py_s + 1) >> 1 > 3 ? 3 : (py_s + 1) >> 1;
  const int ky1 = py_s + 1 - 2 * oy1;
  const bool z2 = (py_s == 0) || (py_s == 7);
  const int oy2 = py_s == 0 ? 0 : (py_s == 7 ? 3 : oy1 - 1);
  const int ky2 = py_s == 0 ? 0 : (py_s == 7 ? 3 : ky1 + 2);
  const unsigned m2 = z2 ? 0u : 0xFFFFFFFFu;

  // B-write dsts for both pairs: ml = bl*16+oy*4+ox, gk = ncs*2+(ky>>1)
  char* bwd1[4];
  char* bwd2[4];
#pragma unroll
  for (int ox = 0; ox < 4; ++ox) {
    const int ml1 = bl_s * 16 + oy1 * 4 + ox;
    const int gk1 = ncs_s * 2 + (ky1 >> 1);
    bwd1[ox] = Bs + ml1 * 64 + ((gk1 ^ ((ml1 >> 1) & 3)) << 4) + ((ky1 & 1) << 3);
    const int ml2 = bl_s * 16 + oy2 * 4 + ox;
    const int gk2 = ncs_s * 2 + (ky2 >> 1);
    bwd2[ox] = Bs + ml2 * 64 + ((gk2 ^ ((ml2 >> 1) & 3)) << 4) + ((ky2 & 1) << 3);
  }

  // -------- weight staging: one task/thread: az0=tid>>3 (0..63), kq=tid&7
  const int az0 = tid >> 3;
  const int kq  = tid & 7;
  const float* const wsrc =
      weight + ((size_t)(g * 256 + z0 + az0)) * 2048 + kq * 4;
  const int aswz = (az0 >> 1) & 3;
  char* const ad0 = As + az0 * 64 + (((kq >> 1) ^ aswz) << 4) + ((kq & 1) << 3);

  // -------- fragment read pointers (identical to R12)
  const char* afp[4];
#pragma unroll
  for (int zf = 0; zf < 4; ++zf) {
    const int ar = zf * 16 + llo;
    afp[zf] = As + ar * 64 + ((lhi ^ ((ar >> 1) & 3)) << 4);
  }
  const char* bfp[4];
#pragma unroll
  for (int mf = 0; mf < 4; ++mf) {
    const int mr = w * 64 + mf * 16 + llo;        // 0..511
    bfp[mf] = Bs + mr * 64 + ((lhi ^ ((mr >> 1) & 3)) << 4);
  }

  f32x4 acc[4][4] = {};

  // pack row -> 5 shared tap-packs; ub[ox] = {pk[ox], pk[ox+1]}
  unsigned pk[5];
  auto packRow = [&](const float4& q0, const float4& q1) {
    pk[0] = packbf(0.f, q0.x);
    pk[1] = packbf(q0.y, q0.z);
    pk[2] = packbf(q0.w, q1.x);
    pk[3] = packbf(q1.y, q1.z);
    pk[4] = packbf(q1.w, 0.f);
  };
  auto writeTiles = [&](unsigned aw) {
    *(uint2*)ad0 = *(uint2*)&aw;  // placeholder; replaced below
  };
  auto domfma = [&]() {
    bf16x8 bfv[4];
#pragma unroll
    for (int mf = 0; mf < 4; ++mf) bfv[mf] = *(const bf16x8*)bfp[mf];
#pragma unroll
    for (int zf = 0; zf < 4; ++zf) {
      const bf16x8 af = *(const bf16x8*)afp[zf];
#pragma unroll
      for (int mf = 0; mf < 4; ++mf)
        acc[zf][mf] = __builtin_amdgcn_mfma_f32_16x16x32_bf16(af, bfv[mf], acc[zf][mf], 0, 0, 0);
    }
  };

  // -------- prologue: prefetch chunks 0,1
  float4 rA0 = *(const float4*)(gsrc);
  float4 rA1 = *(const float4*)(gsrc + 4);
  float4 rB0 = *(const float4*)(gsrc + 8192);
  float4 rB1 = *(const float4*)(gsrc + 8192 + 4);
  float4 wA  = *(const float4*)(wsrc);
  float4 wB  = *(const float4*)(wsrc + 32);

  for (int ck = 0; ck < 64; ck += 2) {
    // ============ even chunk ck ============
    {
      packRow(rA0, rA1);
      uint2 a0w;
      a0w.x = packbf(wA.x, wA.y); a0w.y = packbf(wA.z, wA.w);
      if (ck + 2 < 64) {
        rA0 = *(const float4*)(gsrc + (size_t)(ck + 2) * 8192);
        rA1 = *(const float4*)(gsrc + (size_t)(ck + 2) * 8192 + 4);
        wA  = *(const float4*)(wsrc + (ck + 2) * 32);
      }
      LDS_BARRIER();               // prev MFMAs done reading tiles
      *(uint2*)ad0 = a0w;
#pragma unroll
      for (int ox = 0; ox < 4; ++ox) {
        uint2 t1; t1.x = pk[ox]; t1.y = pk[ox + 1];
        *(uint2*)bwd1[ox] = t1;
        uint2 t2; t2.x = pk[ox] & m2; t2.y = pk[ox + 1] & m2;
        *(uint2*)bwd2[ox] = t2;
      }
      LDS_BARRIER();               // tiles ready
      domfma();
    }
    // ============ odd chunk ck+1 ============
    {
      packRow(rB0, rB1);
      uint2 a0w;
      a0w.x = packbf(wB.x, wB.y); a0w.y = packbf(wB.z, wB.w);
      if (ck + 3 < 64) {
        rB0 = *(const float4*)(gsrc + (size_t)(ck + 3) * 8192);
        rB1 = *(const float4*)(gsrc + (size_t)(ck + 3) * 8192 + 4);
        wB  = *(const float4*)(wsrc + (ck + 3) * 32);
      }
      LDS_BARRIER();
      *(uint2*)ad0 = a0w;
#pragma unroll
      for (int ox = 0; ox < 4; ++ox) {
        uint2 t1; t1.x = pk[ox]; t1.y = pk[ox + 1];
        *(uint2*)bwd1[ox] = t1;
        uint2 t2; t2.x = pk[ox] & m2; t2.y = pk[ox + 1] & m2;
        *(uint2*)bwd2[ox] = t2;
      }
      LDS_BARRIER();
      domfma();
    }
  }

  // ================= block-local BN: stats -> inv/shift -> apply =============
  __syncthreads();                 // all waves done with tiles; reuse Bs
  float* const sums  = (float*)Bs;          // [ch_local 0..63][wave 0..7]
  float* const sums2 = sums + 512;
  float* const invL  = sums2 + 512;         // [64]
  float* const shL   = invL + 64;           // [64]
#pragma unroll
  for (int zf = 0; zf < 4; ++zf) {
    float s[4], ss[4];
#pragma unroll
    for (int r = 0; r < 4; ++r) {
      s[r]  = acc[zf][0][r] + acc[zf][1][r] + acc[zf][2][r] + acc[zf][3][r];
      ss[r] = acc[zf][0][r] * acc[zf][0][r] + acc[zf][1][r] * acc[zf][1][r]
            + acc[zf][2][r] * acc[zf][2][r] + acc[zf][3][r] * acc[zf][3][r];
    }
#pragma unroll
    for (int off = 1; off <= 8; off <<= 1) {
#pragma unroll
      for (int r = 0; r < 4; ++r) {
        s[r]  += __shfl_xor(s[r], off);
        ss[r] += __shfl_xor(ss[r], off);
      }
    }
    if (llo == 0) {
#pragma unroll
      for (int r = 0; r < 4; ++r) {
        const int chl = zf * 16 + lhi * 4 + r;
        sums[chl * 8 + w]  = s[r];
        sums2[chl * 8 + w] = ss[r];
      }
    }
  }
  __syncthreads();
  if (tid < 64) {
    float sum = 0.f, sq = 0.f;
#pragma unroll
    for (int i = 0; i < 8; ++i) { sum += sums[tid * 8 + i]; sq += sums2[tid * 8 + i]; }
    const int ch = g * 256 + z0 + tid;
    const float mean = sum * (1.f / 512.f);
    const float var  = fmaf(-mean, mean, sq * (1.f / 512.f));
    const float iv   = gamma[ch] * rsqrtf(var + kEps);
    invL[tid] = iv;
    shL[tid]  = fmaf(-mean, iv, beta[ch]);
  }
  __syncthreads();

  // -------- apply BN + LeakyReLU in registers; store FINAL to fold layout
#pragma unroll
  for (int zf = 0; zf < 4; ++zf) {
    float iv[4], sh[4];
#pragma unroll
    for (int r = 0; r < 4; ++r) {
      const int chl = zf * 16 + lhi * 4 + r;
      iv[r] = invL[chl];
      sh[r] = shL[chl];
    }
    const int zch = z0 + zf * 16 + lhi * 4;       // + r below
#pragma unroll
    for (int mf = 0; mf < 4; ++mf) {
      const int mm  = w * 64 + mf * 16 + llo;     // 0..511
      const int bb  = mm >> 4;
      const int o_y = (mm >> 2) & 3;
      const int o_x = mm & 3;
      float* op = out + (((size_t)bb * 256 + zch) * 32 + hp * 4 + o_y) * 32
                      + wp * 4 + o_x;
#pragma unroll
      for (int r = 0; r < 4; ++r) {
        float y = fmaf(acc[zf][mf][r], iv[r], sh[r]);
        y = y > 0.f ? y : kLrelu * y;
        op[(size_t)r * 1024] = y;
      }
    }
  }
}

extern "C" void kernel_launch(void* const* d_in, const int* in_sizes, int n_in,
                              void* d_out, int out_size, void* d_ws, size_t ws_size,
                              hipStream_t stream) {
  const float* input  = (const float*)d_in[0];
  const float* weight = (const float*)d_in[1];
  const float* gamma  = (const float*)d_in[2];
  const float* beta   = (const float*)d_in[3];
  float* out = (float*)d_out;

  conv_bn_fused<<<256, 512, 0, stream>>>(input, weight, out, gamma, beta);
}

// Round 14
// 89.762 us; speedup vs baseline: 1.2712x; 1.2712x over previous
//
#include <hip/hip_runtime.h>

namespace {
constexpr float kLrelu = 0.2f;
constexpr float kEps   = 1e-5f;
}

typedef short bf16x8 __attribute__((ext_vector_type(8)));
typedef float f32x4  __attribute__((ext_vector_type(4)));

// LDS-only barrier: waits local ops, does NOT drain vmcnt -> global prefetch
// loads stay in flight across the barrier.
#define LDS_BARRIER() asm volatile("s_waitcnt lgkmcnt(0)\n\ts_barrier" ::: "memory")

// round-to-nearest-even f32 -> bf16 (inputs are finite)
static __device__ __forceinline__ unsigned f2bf(float x) {
  unsigned u = __float_as_uint(x);
  return (u + 0x7FFFu + ((u >> 16) & 1u)) >> 16;
}
static __device__ __forceinline__ unsigned packbf(float a, float b) {
  return f2bf(a) | (f2bf(b) << 16);
}

// Fully fused: grouped conv (bf16 MFMA) + block-local BatchNorm + LeakyReLU +
// fold-layout store. Block = (g, zt): 64 z-channels x ALL 512 m (BN local).
// 256 blocks x 512 threads = 8 waves, wave tile 64z x 64m. Verified R12
// structure (session best: 89.5 us). R13's direct-write variant regressed
// (write-bank parity conflict, 12.7M cyc) -- this is the deliberate revert.
__global__ __launch_bounds__(512, 4) void conv_bn_fused(
    const float* __restrict__ input,   // [32,128,64,64]
    const float* __restrict__ weight,  // [16384, 2048]  (k = nc*16 + ky*4 + kx)
    float* __restrict__ out,           // [32,256,32,32] FINAL (post BN+LReLU)
    const float* __restrict__ gamma,
    const float* __restrict__ beta)
{
  // raw patch tiles: 64 patches (32 b x 2 nc) x 64 floats, row-XOR swizzle:
  //   addr(fl) = pl*64 + ((py ^ (bl&7))<<3) + px        (16 KB per buffer)
  __shared__ __align__(16) float raw0[64 * 64];
  __shared__ __align__(16) float raw1[64 * 64];
  // GEMM tiles, row = 64B (32 bf16), 16B-granule XOR swizzle (gk ^ ((row>>1)&3))
  __shared__ __align__(16) char Bs[512 * 64];     // 32 KB
  __shared__ __align__(16) char As[64 * 64];      // 4 KB

  const int bid  = blockIdx.x;
  const int orig = (bid & 7) * 32 + (bid >> 3);   // XCD-chunked (256 % 8 == 0)
  const int g    = orig >> 2;                     // group 0..63
  const int zt   = orig & 3;                      // z tile 0..3
  const int hp = g >> 3, wp = g & 7;
  const int z0 = zt * 64;

  const int tid  = threadIdx.x;
  const int lane = tid & 63;
  const int w    = tid >> 6;                      // wave 0..7, m-range = w*64
  const int llo  = lane & 15, lhi = lane >> 4;

  // -------- raw staging: two float4/thread/chunk (64 patches x 16 float4)
  const int pl_s  = tid >> 3;                     // patch 0..63
  const int f4    = tid & 7;
  const int bl_s  = pl_s >> 1;                    // b 0..31
  const int ncs_s = pl_s & 1;
  const int py_s  = f4 >> 1, h_s = f4 & 1;
  const float* const gsrc = input
      + ((size_t)bl_s * 128 + ncs_s) * 4096
      + (hp * 8 + py_s) * 64 + wp * 8 + (h_s << 2);   // 2nd load: +256 (py+4)
  const int roffA = pl_s * 64 + ((py_s ^ (bl_s & 7)) << 3) + (h_s << 2);
  const int roffB = pl_s * 64 + (((py_s + 4) ^ (bl_s & 7)) << 3) + (h_s << 2);
  float* const rd0a = raw0 + roffA;  float* const rd0b = raw0 + roffB;
  float* const rd1a = raw1 + roffA;  float* const rd1b = raw1 + roffB;

  // -------- weight staging: one task/thread: az0=tid>>3 (0..63), kq=tid&7
  const int az0 = tid >> 3;
  const int kq  = tid & 7;
  const float* const wsrc =
      weight + ((size_t)(g * 256 + z0 + az0)) * 2048 + kq * 4;
  const int aswz = (az0 >> 1) & 3;
  char* const ad0 = As + az0 * 64 + (((kq >> 1) ^ aswz) << 4) + ((kq & 1) << 3);

  // -------- row-gather: 2 tasks/thread (ncs=0,1): bl=tid>>4, oy, ky
  const int bl_g = tid >> 4;                      // 0..31
  const int oy_g = (tid >> 2) & 3;
  const int ky_g = tid & 3;
  const int iy   = 2 * oy_g - 1 + ky_g;
  const unsigned rowm = ((unsigned)iy < 8u) ? 0xFFFFFFFFu : 0u;
  const int iyc  = iy < 0 ? 0 : (iy > 7 ? 7 : iy);
  const int swzg = bl_g & 7;
  const int gro0 = (bl_g * 2 + 0) * 64 + ((iyc ^ swzg) << 3);
  const int gro1 = (bl_g * 2 + 1) * 64 + ((iyc ^ swzg) << 3);
  // B-write dsts: ml = bl*16+oy*4+ox, byte col = ncs*32 + ky*8
  char* bwd[2][4];
#pragma unroll
  for (int ncs = 0; ncs < 2; ++ncs)
#pragma unroll
    for (int ox = 0; ox < 4; ++ox) {
      const int ml = bl_g * 16 + oy_g * 4 + ox;
      const int gk = ncs * 2 + (ky_g >> 1);
      bwd[ncs][ox] = Bs + ml * 64 + ((gk ^ ((ml >> 1) & 3)) << 4) + ((ky_g & 1) << 3);
    }

  // -------- fragment read pointers
  const char* afp[4];
#pragma unroll
  for (int zf = 0; zf < 4; ++zf) {
    const int ar = zf * 16 + llo;
    afp[zf] = As + ar * 64 + ((lhi ^ ((ar >> 1) & 3)) << 4);
  }
  const char* bfp[4];
#pragma unroll
  for (int mf = 0; mf < 4; ++mf) {
    const int mr = w * 64 + mf * 16 + llo;        // 0..511
    bfp[mf] = Bs + mr * 64 + ((lhi ^ ((mr >> 1) & 3)) << 4);
  }

  f32x4 acc[4][4] = {};

  // tap selects: row[0..7] = r0.xyzw r1.xyzw; tap(ox,kx) = row[2ox-1+kx]
  uint2 ub[2][4];
  auto gather = [&](const float* rw) {
#pragma unroll
    for (int ncs = 0; ncs < 2; ++ncs) {
      const int gro = ncs ? gro1 : gro0;
      const float4 r0 = *(const float4*)(rw + gro);
      const float4 r1 = *(const float4*)(rw + gro + 4);
      uint2 t;
      t.x = packbf(0.f, r0.x) & rowm;  t.y = packbf(r0.y, r0.z) & rowm;  ub[ncs][0] = t;
      t.x = packbf(r0.y, r0.z) & rowm; t.y = packbf(r0.w, r1.x) & rowm;  ub[ncs][1] = t;
      t.x = packbf(r0.w, r1.x) & rowm; t.y = packbf(r1.y, r1.z) & rowm;  ub[ncs][2] = t;
      t.x = packbf(r1.y, r1.z) & rowm; t.y = packbf(r1.w, 0.f) & rowm;   ub[ncs][3] = t;
    }
  };
  auto writeB = [&]() {
#pragma unroll
    for (int ncs = 0; ncs < 2; ++ncs)
#pragma unroll
      for (int ox = 0; ox < 4; ++ox) *(uint2*)bwd[ncs][ox] = ub[ncs][ox];
  };
  auto domfma = [&]() {
    bf16x8 bfv[4];
#pragma unroll
    for (int mf = 0; mf < 4; ++mf) bfv[mf] = *(const bf16x8*)bfp[mf];
#pragma unroll
    for (int zf = 0; zf < 4; ++zf) {
      const bf16x8 af = *(const bf16x8*)afp[zf];
#pragma unroll
      for (int mf = 0; mf < 4; ++mf)
        acc[zf][mf] = __builtin_amdgcn_mfma_f32_16x16x32_bf16(af, bfv[mf], acc[zf][mf], 0, 0, 0);
    }
  };

  // -------- prologue: prefetch chunks 0,1; stage chunk 0 into raw0
  float4 ra0 = *(const float4*)(gsrc);
  float4 ra1 = *(const float4*)(gsrc + 256);
  float4 rb0 = *(const float4*)(gsrc + 8192);
  float4 rb1 = *(const float4*)(gsrc + 8192 + 256);
  float4 wa  = *(const float4*)(wsrc);
  float4 wb  = *(const float4*)(wsrc + 32);
  *(float4*)rd0a = ra0;
  *(float4*)rd0b = ra1;
  LDS_BARRIER();

  for (int ck = 0; ck < 64; ck += 2) {
    // ============ even chunk ck (gather raw0, stage ck+1 -> raw1) ============
    {
      uint2 a0w;
      a0w.x = packbf(wa.x, wa.y); a0w.y = packbf(wa.z, wa.w);
      if (ck + 2 < 64) {
        ra0 = *(const float4*)(gsrc + (size_t)(ck + 2) * 8192);
        ra1 = *(const float4*)(gsrc + (size_t)(ck + 2) * 8192 + 256);
        wa  = *(const float4*)(wsrc + (ck + 2) * 32);
      }
      gather(raw0);
      LDS_BARRIER();               // prev MFMAs + this gather done reading LDS
      *(uint2*)ad0 = a0w;
      writeB();
      *(float4*)rd1a = rb0;        // stage chunk ck+1 (loaded 2 phases ago)
      *(float4*)rd1b = rb1;
      LDS_BARRIER();               // tiles + raw1 visible
      domfma();
    }
    // ============ odd chunk ck+1 (gather raw1, stage ck+2 -> raw0) ===========
    {
      uint2 a0w;
      a0w.x = packbf(wb.x, wb.y); a0w.y = packbf(wb.z, wb.w);
      if (ck + 3 < 64) {
        rb0 = *(const float4*)(gsrc + (size_t)(ck + 3) * 8192);
        rb1 = *(const float4*)(gsrc + (size_t)(ck + 3) * 8192 + 256);
        wb  = *(const float4*)(wsrc + (ck + 3) * 32);
      }
      gather(raw1);
      LDS_BARRIER();
      *(uint2*)ad0 = a0w;
      writeB();
      if (ck + 2 < 64) { *(float4*)rd0a = ra0; *(float4*)rd0b = ra1; }
      LDS_BARRIER();
      domfma();
    }
  }

  // ================= block-local BN: stats -> inv/shift -> apply =============
  __syncthreads();                 // all waves done with tiles; reuse raw0/raw1
  float* const sums  = (float*)raw0;        // [ch_local 0..63][wave 0..7]
  float* const sums2 = sums + 512;
#pragma unroll
  for (int zf = 0; zf < 4; ++zf) {
    float s[4], ss[4];
#pragma unroll
    for (int r = 0; r < 4; ++r) {
      s[r]  = acc[zf][0][r] + acc[zf][1][r] + acc[zf][2][r] + acc[zf][3][r];
      ss[r] = acc[zf][0][r] * acc[zf][0][r] + acc[zf][1][r] * acc[zf][1][r]
            + acc[zf][2][r] * acc[zf][2][r] + acc[zf][3][r] * acc[zf][3][r];
    }
#pragma unroll
    for (int off = 1; off <= 8; off <<= 1) {
#pragma unroll
      for (int r = 0; r < 4; ++r) {
        s[r]  += __shfl_xor(s[r], off);
        ss[r] += __shfl_xor(ss[r], off);
      }
    }
    if (llo == 0) {
#pragma unroll
      for (int r = 0; r < 4; ++r) {
        const int chl = zf * 16 + lhi * 4 + r;
        sums[chl * 8 + w]  = s[r];
        sums2[chl * 8 + w] = ss[r];
      }
    }
  }
  __syncthreads();
  float* const invL = (float*)raw1;         // [64]
  float* const shL  = invL + 64;            // [64]
  if (tid < 64) {
    float sum = 0.f, sq = 0.f;
#pragma unroll
    for (int i = 0; i < 8; ++i) { sum += sums[tid * 8 + i]; sq += sums2[tid * 8 + i]; }
    const int ch = g * 256 + z0 + tid;
    const float mean = sum * (1.f / 512.f);
    const float var  = fmaf(-mean, mean, sq * (1.f / 512.f));
    const float iv   = gamma[ch] * rsqrtf(var + kEps);
    invL[tid] = iv;
    shL[tid]  = fmaf(-mean, iv, beta[ch]);
  }
  __syncthreads();

  // -------- apply BN + LeakyReLU in registers; store FINAL to fold layout
#pragma unroll
  for (int zf = 0; zf < 4; ++zf) {
    float iv[4], sh[4];
#pragma unroll
    for (int r = 0; r < 4; ++r) {
      const int chl = zf * 16 + lhi * 4 + r;
      iv[r] = invL[chl];
      sh[r] = shL[chl];
    }
    const int zch = z0 + zf * 16 + lhi * 4;       // + r below
#pragma unroll
    for (int mf = 0; mf < 4; ++mf) {
      const int mm  = w * 64 + mf * 16 + llo;     // 0..511
      const int bb  = mm >> 4;
      const int o_y = (mm >> 2) & 3;
      const int o_x = mm & 3;
      float* op = out + (((size_t)bb * 256 + zch) * 32 + hp * 4 + o_y) * 32
                      + wp * 4 + o_x;
#pragma unroll
      for (int r = 0; r < 4; ++r) {
        float y = fmaf(acc[zf][mf][r], iv[r], sh[r]);
        y = y > 0.f ? y : kLrelu * y;
        op[(size_t)r * 1024] = y;
      }
    }
  }
}

extern "C" void kernel_launch(void* const* d_in, const int* in_sizes, int n_in,
                              void* d_out, int out_size, void* d_ws, size_t ws_size,
                              hipStream_t stream) {
  const float* input  = (const float*)d_in[0];
  const float* weight = (const float*)d_in[1];
  const float* gamma  = (const float*)d_in[2];
  const float* beta   = (const float*)d_in[3];
  float* out = (float*)d_out;

  conv_bn_fused<<<256, 512, 0, stream>>>(input, weight, out, gamma, beta);
}